// Round 15
// baseline (449.655 us; speedup 1.0000x reference)
//
#include <hip/hip_runtime.h>
#include <hip/hip_bf16.h>
#include <math.h>

#define B_ 64
#define N_ 1024
#define E_ 16

typedef unsigned short ushort_t;
typedef __attribute__((ext_vector_type(8))) short bf16x8;
typedef __attribute__((ext_vector_type(4))) float f32x4;

__device__ __forceinline__ float sigmoidf_(float x) {
  return 1.0f / (1.0f + __expf(-x));
}
__device__ __forceinline__ ushort_t f2bf(float f) {  // RNE
  unsigned int u = __float_as_uint(f);
  u = (u + 0x7fffu + ((u >> 16) & 1u)) >> 16;
  return (ushort_t)u;
}
__device__ __forceinline__ float bf2f(ushort_t h) { return __uint_as_float((unsigned)h << 16); }
__device__ __forceinline__ void gload16(const void* g, void* l) {
  __builtin_amdgcn_global_load_lds(
      (const __attribute__((address_space(1))) unsigned int*)g,
      (__attribute__((address_space(3))) unsigned int*)l, 16, 0, 0);
}

// ---------- A = softmax(relu(emb@emb^T)) -> hi/lo bf16 [n][m] (rows 0-1023 of stack) ----------
__global__ __launch_bounds__(256) void compute_A_kernel(const float* __restrict__ emb,
                                                        ushort_t* __restrict__ Ah,
                                                        ushort_t* __restrict__ Al) {
  __shared__ float embn[E_];
  __shared__ float red[256];
  const int n = blockIdx.x;
  const int t = threadIdx.x;
  if (t < E_) embn[t] = emb[n * E_ + t];
  __syncthreads();
  float s[4];
#pragma unroll
  for (int j = 0; j < 4; ++j) {
    const int m = j * 256 + t;
    const float* em = emb + m * E_;
    float acc = 0.f;
#pragma unroll
    for (int d = 0; d < E_; ++d) acc = fmaf(embn[d], em[d], acc);
    s[j] = fmaxf(acc, 0.f);
  }
  float mx = fmaxf(fmaxf(s[0], s[1]), fmaxf(s[2], s[3]));
  red[t] = mx;
  __syncthreads();
  for (int off = 128; off > 0; off >>= 1) {
    if (t < off) red[t] = fmaxf(red[t], red[t + off]);
    __syncthreads();
  }
  mx = red[0];
  __syncthreads();
  float e[4], lsum = 0.f;
#pragma unroll
  for (int j = 0; j < 4; ++j) { e[j] = __expf(s[j] - mx); lsum += e[j]; }
  red[t] = lsum;
  __syncthreads();
  for (int off = 128; off > 0; off >>= 1) {
    if (t < off) red[t] += red[t + off];
    __syncthreads();
  }
  const float inv = 1.0f / red[0];
#pragma unroll
  for (int j = 0; j < 4; ++j) {
    const float v = e[j] * inv;
    ushort_t h = f2bf(v);
    Ah[n * N_ + j * 256 + t] = h;
    Al[n * N_ + j * 256 + t] = f2bf(v - bf2f(h));
  }
}

// ---------- At[j][m] = A[m][j] for hi and lo (LDS tile transpose) ----------
__global__ __launch_bounds__(256) void transpose_A_kernel(const ushort_t* __restrict__ src1,
                                                          ushort_t* __restrict__ dst1,
                                                          const ushort_t* __restrict__ src2,
                                                          ushort_t* __restrict__ dst2) {
  __shared__ ushort_t tile[128][130];
  const int t = threadIdx.x;
  const int r0 = blockIdx.y << 7, c0 = blockIdx.x << 7;
  const ushort_t* src = src1;
  ushort_t* dst = dst1;
#pragma unroll
  for (int p = 0; p < 2; ++p) {
    if (p) { src = src2; dst = dst2; __syncthreads(); }
#pragma unroll
    for (int it = 0; it < 8; ++it) {
      const int id = it * 256 + t;
      const int row = id >> 4, ch = (id & 15) << 3;
      *(uint4*)&tile[row][ch] = *(const uint4*)&src[(size_t)(r0 + row) * 1024 + c0 + ch];
    }
    __syncthreads();
#pragma unroll
    for (int it = 0; it < 8; ++it) {
      const int id = it * 256 + t;
      const int row = id >> 4, ch = (id & 15) << 3;
      ushort_t v[8];
#pragma unroll
      for (int u = 0; u < 8; ++u) v[u] = tile[ch + u][row];
      *(uint4*)&dst[(size_t)(c0 + row) * 1024 + r0 + ch] = *(const uint4*)v;
    }
    __syncthreads();
  }
}

// ---------- cat(xA,xB)[b][n][c] -> T0t hi/lo [(b*128+c)][n] ----------
__global__ __launch_bounds__(256) void build_T0t_kernel(const float* __restrict__ xA,
                                                        const float* __restrict__ xB,
                                                        ushort_t* __restrict__ Th,
                                                        ushort_t* __restrict__ Tl) {
  __shared__ float tile[128][129];  // [c][n-local]
  const int t = threadIdx.x;
  const int b = blockIdx.y;
  const int n0 = blockIdx.x << 7;
  const int c4 = (t & 31) << 2, nl = t >> 5;
#pragma unroll
  for (int p = 0; p < 16; ++p) {
    const int n = nl + (p << 3);
    const float4 v = (c4 < 64)
        ? *(const float4*)&xA[((size_t)b << 16) + ((size_t)(n0 + n) << 6) + c4]
        : *(const float4*)&xB[((size_t)b << 16) + ((size_t)(n0 + n) << 6) + c4 - 64];
    tile[c4 + 0][n] = v.x; tile[c4 + 1][n] = v.y;
    tile[c4 + 2][n] = v.z; tile[c4 + 3][n] = v.w;
  }
  __syncthreads();
  const int c = t >> 1, nc = (t & 1) << 6;
  const size_t obase = ((size_t)(b << 7) + c) * 1024 + n0 + nc;
#pragma unroll
  for (int u = 0; u < 64; u += 4) {
    ushort4 h, l;
    float v0 = tile[c][nc + u + 0], v1 = tile[c][nc + u + 1];
    float v2 = tile[c][nc + u + 2], v3 = tile[c][nc + u + 3];
    h.x = f2bf(v0); l.x = f2bf(v0 - bf2f(h.x));
    h.y = f2bf(v1); l.y = f2bf(v1 - bf2f(h.y));
    h.z = f2bf(v2); l.z = f2bf(v2 - bf2f(h.z));
    h.w = f2bf(v3); l.w = f2bf(v3 - bf2f(h.w));
    *(ushort4*)&Th[obase + u] = h;
    *(ushort4*)&Tl[obase + u] = l;
  }
}

// ---------- rs[b][n][64] -> T0s hi/lo [(b*64+c)][n]  (update pass, s-half only) ----------
__global__ __launch_bounds__(256) void build_T0s_kernel(const float* __restrict__ rs,
                                                        ushort_t* __restrict__ Th,
                                                        ushort_t* __restrict__ Tl) {
  __shared__ float tile[64][129];  // [c][n-local]
  const int t = threadIdx.x;
  const int b = blockIdx.y;
  const int n0 = blockIdx.x << 7;
  const int c4 = (t & 15) << 2, nl = t >> 4;
#pragma unroll
  for (int p = 0; p < 8; ++p) {
    const int n = nl + (p << 4);
    const float4 v = *(const float4*)&rs[((size_t)b << 16) + ((size_t)(n0 + n) << 6) + c4];
    tile[c4 + 0][n] = v.x; tile[c4 + 1][n] = v.y;
    tile[c4 + 2][n] = v.z; tile[c4 + 3][n] = v.w;
  }
  __syncthreads();
  const int c = t >> 2, nc = (t & 3) << 5;
  const size_t obase = ((size_t)(b << 6) + c) * 1024 + n0 + nc;
#pragma unroll
  for (int u = 0; u < 32; u += 4) {
    ushort4 h, l;
    float v0 = tile[c][nc + u + 0], v1 = tile[c][nc + u + 1];
    float v2 = tile[c][nc + u + 2], v3 = tile[c][nc + u + 3];
    h.x = f2bf(v0); l.x = f2bf(v0 - bf2f(h.x));
    h.y = f2bf(v1); l.y = f2bf(v1 - bf2f(h.y));
    h.z = f2bf(v2); l.z = f2bf(v2 - bf2f(h.z));
    h.w = f2bf(v3); l.w = f2bf(v3 - bf2f(h.w));
    *(ushort4*)&Th[obase + u] = h;
    *(ushort4*)&Tl[obase + u] = l;
  }
}

// ---------- MFMA split-bf16 GEMM, BK=32 double-buffer + COUNTED vmcnt + raw barriers ----------
// D[n][j] = sum_m (Ah+Al)[n][m] * (Bh+Bl)[j][m]
// MODE 0: stacked diffusion — rows 0-1023 = A (-> Xp slot 0), 1024-2047 = M=2A^2 (-> slot 128).
//         SPAN 128: gate; SPAN 64: update (j=b*64+cs -> Xp offset 64+cs).
// MODE 1: M-writer — v = 2*acc, row-major OutH/OutL [n][j].
// LDS per buffer per array: 8 KB as [64 vrow][128B]; vrow v packs real rows 2v,2v+1
// (32 k each); byte-within-vrow XOR-swizzled by ((v&7)<<4), pre-swizzled at source.
// Pipeline: STAGE(k+1) -> s_waitcnt vmcnt(8) (tile k's loads done; k+1's stay in
// flight across the barrier) -> raw s_barrier -> MFMA(k) -> raw s_barrier.
template <int MODE, int SPAN>
__global__ __launch_bounds__(256, 2) void mfma_gemm_kernel(
    const ushort_t* __restrict__ Ah, const ushort_t* __restrict__ Al,   // stacked [2048][1024]
    const ushort_t* __restrict__ Bh, const ushort_t* __restrict__ Bl,   // [NJ][1024]
    ushort_t* __restrict__ OutH, ushort_t* __restrict__ OutL) {
  __shared__ ushort_t smem[2 * 4 * 4096];  // 64 KB: [buf][arr][4096 ushorts]
  const int t = threadIdx.x;
  const int wave = t >> 6, lane = t & 63;
  const int n0 = blockIdx.y << 7;   // stacked row base
  const int bcol = blockIdx.x;
  const int j0 = bcol << 7;
  const int wr = wave >> 1, wc = wave & 1;
  const int fr = lane & 15, fq = lane >> 4;

  f32x4 acc[4][4];
#pragma unroll
  for (int i = 0; i < 4; ++i)
#pragma unroll
    for (int j = 0; j < 4; ++j) acc[i][j] = (f32x4){0.f, 0.f, 0.f, 0.f};

  // staging constants (per thread) — verified bit-exact in R11/R12
  const int lr3 = lane >> 3;            // 0..7
  const int cs = (lane & 7) ^ lr3;      // pre-swizzled source chunk
  const int rofs = (cs >> 2);           // which real row of the vrow pair
  const int kkofs = (cs & 3) << 3;      // k element offset within row's 32
  auto STAGE = [&](int bsel, int kb) {  // 8 global_load_lds per wave
#pragma unroll
    for (int i = 0; i < 2; ++i) {
      const int q = (wave << 1) + i;              // 0..7
      const int v = (q << 3) + lr3;               // vrow 0..63
      const int r = (v << 1) + rofs;              // real row 0..127
      const int lo = bsel * 16384 + q * 512 + lane * 8;  // ushort offset
      const size_t ga = (size_t)(n0 + r) * 1024 + kb + kkofs;
      const size_t gb = (size_t)(j0 + r) * 1024 + kb + kkofs;
      gload16(Ah + ga, smem + lo);
      gload16(Al + ga, smem + 4096 + lo);
      gload16(Bh + gb, smem + 8192 + lo);
      gload16(Bl + gb, smem + 12288 + lo);
    }
  };
  auto FRAG = [&](const ushort_t* arrbase, int r) -> bf16x8 {
    const int v = r >> 1;
    const int b = ((((r & 1) << 2) | fq) ^ (v & 7)) << 4;
    return *(const bf16x8*)((const char*)arrbase + v * 128 + b);
  };

  STAGE(0, 0);
  for (int k = 0; k < 32; ++k) {
    if (k < 31) {
      STAGE((k + 1) & 1, (k + 1) << 5);
      asm volatile("s_waitcnt vmcnt(8)" ::: "memory");  // tile k complete; k+1 in flight
    } else {
      asm volatile("s_waitcnt vmcnt(0)" ::: "memory");
    }
    __builtin_amdgcn_s_barrier();                        // raw barrier (no drain)
    __builtin_amdgcn_sched_barrier(0);
    const ushort_t* cb = smem + (k & 1) * 16384;
    bf16x8 ah[4], al[4], bh[4], bl[4];
#pragma unroll
    for (int mi = 0; mi < 4; ++mi) {
      const int r = (wr << 6) + (mi << 4) + fr;
      ah[mi] = FRAG(cb, r);
      al[mi] = FRAG(cb + 4096, r);
    }
#pragma unroll
    for (int nj = 0; nj < 4; ++nj) {
      const int r = (wc << 6) + (nj << 4) + fr;
      bh[nj] = FRAG(cb + 8192, r);
      bl[nj] = FRAG(cb + 12288, r);
    }
#pragma unroll
    for (int mi = 0; mi < 4; ++mi)
#pragma unroll
      for (int nj = 0; nj < 4; ++nj) {
        acc[mi][nj] = __builtin_amdgcn_mfma_f32_16x16x32_bf16(ah[mi], bh[nj], acc[mi][nj], 0, 0, 0);
        acc[mi][nj] = __builtin_amdgcn_mfma_f32_16x16x32_bf16(ah[mi], bl[nj], acc[mi][nj], 0, 0, 0);
        acc[mi][nj] = __builtin_amdgcn_mfma_f32_16x16x32_bf16(al[mi], bh[nj], acc[mi][nj], 0, 0, 0);
      }
    __builtin_amdgcn_s_barrier();                        // reads of buf done before overwrite
    __builtin_amdgcn_sched_barrier(0);
  }

  // epilogue: reuse smem as [128][128] hi/lo transpose tiles
  __syncthreads();
  ushort_t* hiT = smem;            // 32 KB
  ushort_t* loT = smem + 16384;    // 32 KB
#pragma unroll
  for (int mi = 0; mi < 4; ++mi) {
    const int nl = (wr << 6) + (mi << 4) + (fq << 2);
#pragma unroll
    for (int nj = 0; nj < 4; ++nj) {
      const int jl = (wc << 6) + (nj << 4) + fr;
      const f32x4 vv = acc[mi][nj];
#pragma unroll
      for (int r = 0; r < 4; ++r) {
        const float v = (MODE == 1) ? 2.0f * vv[r] : vv[r];
        const ushort_t h = f2bf(v);
        hiT[(nl + r) * 128 + jl] = h;
        loT[(nl + r) * 128 + jl] = f2bf(v - bf2f(h));
      }
    }
  }
  __syncthreads();
  const int soff = (n0 >= 1024) ? 128 : 0;
  const int n0e = n0 & 1023;
#pragma unroll
  for (int rr = 0; rr < 8; ++rr) {
    const int id = rr * 256 + t;     // 2048 16B-chunks
    const int nl = id >> 4, ch = id & 15;
    size_t dstE;
    if (MODE == 1) {
      dstE = (size_t)(n0 + nl) * 1024 + j0 + ch * 8;
    } else if (SPAN == 128) {
      dstE = ((size_t)(n0e + nl) * 64 + bcol) * 256 + soff + ch * 8;
    } else {
      const int bb = bcol * 2 + (ch >> 3);
      dstE = ((size_t)(n0e + nl) * 64 + bb) * 256 + soff + 64 + (ch & 7) * 8;
    }
    *(uint4*)&OutH[dstE] = *(const uint4*)((const char*)hiT + nl * 256 + ch * 16);
    *(uint4*)&OutL[dstE] = *(const uint4*)((const char*)loT + nl * 256 + ch * 16);
  }
}

// ---------- pool transpose: WpT[o][ki][d] = Wp[d][k][i][o] (- Wp[d][2][i][o] if k==0) ----------
template <int OW>  // 128 gate, 64 update
__global__ __launch_bounds__(256) void wpt_kernel(const float* __restrict__ Wp,
                                                  float* __restrict__ WpT) {
  const int idx = blockIdx.x * 256 + threadIdx.x;  // OW*384
  const int ki = idx % 384;
  const int k = ki >> 7, i = ki & 127;
  const int o = idx / 384;
  float v[16];
#pragma unroll
  for (int d = 0; d < 16; ++d) v[d] = Wp[((size_t)d * 384 + ki) * OW + o];
  if (k == 0) {
#pragma unroll
    for (int d = 0; d < 16; ++d) v[d] -= Wp[((size_t)d * 384 + 256 + i) * OW + o];
  }
  float* dst = WpT + (size_t)idx * 16;
#pragma unroll
  for (int q = 0; q < 4; ++q) *(float4*)&dst[q * 4] = *(const float4*)&v[q * 4];
}

// ---------- reg-cached combine: Wt[o][n][ki] hi/lo = sum_d emb[n][d]*WpT[o][ki][d] ----------
// block = (one o, 128 nodes): 512 blocks (2/CU) for write-BW parallelism
__global__ __launch_bounds__(384) void wcombine5_kernel(const float* __restrict__ emb,
                                                        const float* __restrict__ WpT,  // [64][384][16] pre-offset
                                                        ushort_t* __restrict__ WtH,
                                                        ushort_t* __restrict__ WtL) {
  __shared__ float embs[128 * 16];      // 8 KB
  __shared__ ushort_t sH[8 * 384];      // 6 KB
  __shared__ ushort_t sL[8 * 384];      // 6 KB
  const int t = threadIdx.x;            // 0..383 = ki
  const int o = blockIdx.y;             // 0..63
  const int n0 = blockIdx.x << 7;       // node group of 128
  for (int i = t; i < 512; i += 384)
    *(float4*)&embs[i * 4] = *(const float4*)&emb[(size_t)n0 * 16 + i * 4];
  float wreg[16];
  {
    const float* src = WpT + (size_t)o * 6144 + t * 16;
#pragma unroll
    for (int q = 0; q < 4; ++q) *(float4*)&wreg[q * 4] = *(const float4*)&src[q * 4];
  }
  __syncthreads();
  for (int g = 0; g < 16; ++g) {
#pragma unroll
    for (int nl = 0; nl < 8; ++nl) {
      const float* e = &embs[(g * 8 + nl) * 16];
      float a = 0.f;
#pragma unroll
      for (int d = 0; d < 16; ++d) a = fmaf(e[d], wreg[d], a);
      const ushort_t h = f2bf(a);
      sH[nl * 384 + t] = h;
      sL[nl * 384 + t] = f2bf(a - bf2f(h));
    }
    __syncthreads();
    const size_t ob = ((size_t)o * 1024 + n0 + g * 8) * 384 + t * 8;
    *(uint4*)&WtH[ob] = *(const uint4*)&sH[t * 8];
    *(uint4*)&WtL[ob] = *(const uint4*)&sL[t * 8];
    __syncthreads();
  }
}

// ---------- per-node MFMA contraction (O=64) + GRU epilogue ----------
// MODE 0: dst = sigmoid(a)                  (z -> d_out)
// MODE 1: dst = sigmoid(a) * state          (rs)
// MODE 2: dst = zb*state + (1-zb)*tanh(a)   (final out)
template <int MODE>
__global__ __launch_bounds__(256, 2) void pernode_mfma_kernel(
    const float* __restrict__ xA, const float* __restrict__ xB,   // [b][n][64]
    const ushort_t* __restrict__ XpH, const ushort_t* __restrict__ XpL,  // [n][64][256]
    const ushort_t* __restrict__ WtH, const ushort_t* __restrict__ WtL,  // [o][n][384]
    const float* __restrict__ emb, const float* __restrict__ bsrc, int bstride,
    const float* __restrict__ state, const float* __restrict__ zb,
    float* __restrict__ dst) {
  __shared__ ushort_t xh_s[64 * 128];  // 16 KB each
  __shared__ ushort_t xl_s[64 * 128];
  __shared__ ushort_t wh_s[64 * 128];
  __shared__ ushort_t wl_s[64 * 128];
  __shared__ float embn[E_];
  __shared__ float bias[64];
  const int n = blockIdx.x;
  const int t = threadIdx.x;
  if (t < E_) embn[t] = emb[n * E_ + t];
  __syncthreads();
  if (t < 64) {
    float a = 0.f;
#pragma unroll
    for (int d = 0; d < E_; ++d) a = fmaf(embn[d], bsrc[d * bstride + t], a);
    bias[t] = a;
  }
  const int wave = t >> 6, lane = t & 63;
  const int fr = lane & 15, fq = lane >> 4;
  f32x4 acc[4];
#pragma unroll
  for (int i = 0; i < 4; ++i) acc[i] = (f32x4){0.f, 0.f, 0.f, 0.f};

#pragma unroll
  for (int s = 0; s < 3; ++s) {
    __syncthreads();
    if (s == 0) {  // k0 = concat(xA, xB) f32 -> hi/lo bf16, swizzled ds_write
      const int b = t >> 2, q = t & 3;
      const float* srcp = (q < 2)
          ? xA + ((size_t)b << 16) + ((size_t)n << 6) + (q << 5)
          : xB + ((size_t)b << 16) + ((size_t)n << 6) + ((q - 2) << 5);
      float v[32];
#pragma unroll
      for (int j = 0; j < 8; ++j) *(float4*)&v[j * 4] = *(const float4*)&srcp[j * 4];
      const int swz = (b & 7) << 4;
#pragma unroll
      for (int jc = 0; jc < 4; ++jc) {
        unsigned int hh[4], ll[4];
#pragma unroll
        for (int e = 0; e < 4; ++e) {
          const float a0 = v[jc * 8 + 2 * e], a1 = v[jc * 8 + 2 * e + 1];
          const ushort_t h0 = f2bf(a0), h1 = f2bf(a1);
          const ushort_t l0 = f2bf(a0 - bf2f(h0)), l1 = f2bf(a1 - bf2f(h1));
          hh[e] = (unsigned)h0 | ((unsigned)h1 << 16);
          ll[e] = (unsigned)l0 | ((unsigned)l1 << 16);
        }
        const int dstb = b * 256 + (((q << 6) + (jc << 4)) ^ swz);
        *(uint4*)((char*)xh_s + dstb) = make_uint4(hh[0], hh[1], hh[2], hh[3]);
        *(uint4*)((char*)xl_s + dstb) = make_uint4(ll[0], ll[1], ll[2], ll[3]);
      }
    } else {  // Xp slots via global_load_lds, pre-swizzled source
#pragma unroll
      for (int r = 0; r < 4; ++r) {
        const int id = r * 256 + t;
        const int row = id >> 4, ch = id & 15;
        const int selem = (((ch << 4) ^ ((row & 7) << 4)) >> 1);
        const size_t so = ((size_t)n * 64 + row) * 256 + (s - 1) * 128 + selem;
        gload16(XpH + so, xh_s + id * 8);
        gload16(XpL + so, xl_s + id * 8);
      }
    }
#pragma unroll
    for (int r = 0; r < 4; ++r) {
      const int id = r * 256 + t;
      const int row = id >> 4, ch = id & 15;
      const int selem = (((ch << 4) ^ ((row & 7) << 4)) >> 1);
      const size_t so = ((size_t)row * 1024 + n) * 384 + s * 128 + selem;  // Wt[o][n][ki]
      gload16(WtH + so, wh_s + id * 8);
      gload16(WtL + so, wl_s + id * 8);
    }
    __syncthreads();
#pragma unroll
    for (int ks = 0; ks < 4; ++ks) {
      bf16x8 ah[4], al[4];
#pragma unroll
      for (int mi = 0; mi < 4; ++mi) {
        const int r = (mi << 4) + fr;
        const int kb = ((ks << 6) + (fq << 4)) ^ ((r & 7) << 4);
        ah[mi] = *(const bf16x8*)((const char*)xh_s + r * 256 + kb);
        al[mi] = *(const bf16x8*)((const char*)xl_s + r * 256 + kb);
      }
      const int rw = (wave << 4) + fr;
      const int kbw = ((ks << 6) + (fq << 4)) ^ ((rw & 7) << 4);
      const bf16x8 wh = *(const bf16x8*)((const char*)wh_s + rw * 256 + kbw);
      const bf16x8 wl = *(const bf16x8*)((const char*)wl_s + rw * 256 + kbw);
#pragma unroll
      for (int mi = 0; mi < 4; ++mi) {
        acc[mi] = __builtin_amdgcn_mfma_f32_16x16x32_bf16(ah[mi], wh, acc[mi], 0, 0, 0);
        acc[mi] = __builtin_amdgcn_mfma_f32_16x16x32_bf16(al[mi], wh, acc[mi], 0, 0, 0);
        acc[mi] = __builtin_amdgcn_mfma_f32_16x16x32_bf16(ah[mi], wl, acc[mi], 0, 0, 0);
      }
    }
  }

  const int o = (wave << 4) + fr;
  const float bia = bias[o];
#pragma unroll
  for (int mi = 0; mi < 4; ++mi) {
    const int b0 = (mi << 4) + (fq << 2);
    const f32x4 vv = acc[mi];
#pragma unroll
    for (int r = 0; r < 4; ++r) {
      const int b = b0 + r;
      const size_t base = ((size_t)b << 16) + ((size_t)n << 6);
      const float a = vv[r] + bia;
      if (MODE == 0) {
        dst[base + o] = sigmoidf_(a);
      } else if (MODE == 1) {
        dst[base + o] = sigmoidf_(a) * state[base + o];
      } else {
        const float z = zb[base + o], st = state[base + o];
        dst[base + o] = z * st + (1.f - z) * tanhf(a);
      }
    }
  }
}

extern "C" void kernel_launch(void* const* d_in, const int* in_sizes, int n_in,
                              void* d_out, int out_size, void* d_ws, size_t ws_size,
                              hipStream_t stream) {
  const float* x     = (const float*)d_in[0];
  const float* state = (const float*)d_in[1];
  const float* emb   = (const float*)d_in[2];
  const float* Wg    = (const float*)d_in[3];
  const float* bg    = (const float*)d_in[4];
  const float* Wu    = (const float*)d_in[5];
  const float* bu    = (const float*)d_in[6];
  float* out = (float*)d_out;

  char* w = (char*)d_ws;
  ushort_t* AhS  = (ushort_t*)(w);                             // 4 MB [2048][1024]: A rows 0-1023, M rows 1024-2047
  ushort_t* AlS  = (ushort_t*)(w + ((size_t)4 << 20));         // 4
  ushort_t* Ath  = (ushort_t*)(w + ((size_t)8 << 20));         // 2
  ushort_t* Atl  = (ushort_t*)(w + ((size_t)10 << 20));        // 2
  ushort_t* T0th = (ushort_t*)(w + ((size_t)12 << 20));        // 16 (update reuses as T0s)
  ushort_t* T0tl = (ushort_t*)(w + ((size_t)28 << 20));        // 16
  ushort_t* XpH  = (ushort_t*)(w + ((size_t)44 << 20));        // 32  [n][64][256]
  ushort_t* XpL  = (ushort_t*)(w + ((size_t)76 << 20));        // 32
  ushort_t* WtH  = (ushort_t*)(w + ((size_t)108 << 20));       // 48  [o][n][384]
  ushort_t* WtL  = (ushort_t*)(w + ((size_t)156 << 20));       // 48
  float*    rs   = (float*)(w + ((size_t)204 << 20));          // 16
  float*    WpTg = (float*)(w + ((size_t)220 << 20));          // 3   [128][384][16]
  float*    WpTu = (float*)(w + ((size_t)223 << 20));          // 1.5 -> 224.5 MB
  ushort_t* Mh = AhS + (size_t)1024 * 1024;
  ushort_t* Ml = AlS + (size_t)1024 * 1024;
  float* zb = out;

  const dim3 ggd(64, 16);  // gate diffusion (stacked A+M rows)
  const dim3 gud(32, 16);  // update diffusion (s-half cols)
  const dim3 gm(8, 8);     // M-GEMM / transpose
  const dim3 gt(8, 64);
  const dim3 gc(8, 64);    // combine: (n-groups of 128, o)

  compute_A_kernel<<<N_, 256, 0, stream>>>(emb, AhS, AlS);
  transpose_A_kernel<<<gm, 256, 0, stream>>>(AhS, Ath, AlS, Atl);
  mfma_gemm_kernel<1, 128><<<gm, 256, 0, stream>>>(AhS, AlS, Ath, Atl, Mh, Ml);  // M = 2*A*A
  wpt_kernel<128><<<192, 256, 0, stream>>>(Wg, WpTg);
  wpt_kernel<64><<<96, 256, 0, stream>>>(Wu, WpTu);

  // ---- gate pass: one stacked GEMM computes Y1 = A*T0 and Y2 = M*T0 ----
  build_T0t_kernel<<<gt, 256, 0, stream>>>(x, state, T0th, T0tl);
  mfma_gemm_kernel<0, 128><<<ggd, 256, 0, stream>>>(AhS, AlS, T0th, T0tl, XpH, XpL);
  wcombine5_kernel<<<gc, 384, 0, stream>>>(emb, WpTg, WtH, WtL);
  pernode_mfma_kernel<0><<<N_, 256, 0, stream>>>(x, state, XpH, XpL, WtH, WtL, emb, bg, 128,
                                                 state, nullptr, zb);
  wcombine5_kernel<<<gc, 384, 0, stream>>>(emb, WpTg + (size_t)64 * 6144, WtH, WtL);
  pernode_mfma_kernel<1><<<N_, 256, 0, stream>>>(x, state, XpH, XpL, WtH, WtL, emb, bg + 64, 128,
                                                 state, nullptr, rs);

  // ---- update pass: diffuse only rs-half; x diffusion persists from gate ----
  wcombine5_kernel<<<gc, 384, 0, stream>>>(emb, WpTu, WtH, WtL);
  build_T0s_kernel<<<gt, 256, 0, stream>>>(rs, T0th, T0tl);
  mfma_gemm_kernel<0, 64><<<gud, 256, 0, stream>>>(AhS, AlS, T0th, T0tl, XpH, XpL);
  pernode_mfma_kernel<2><<<N_, 256, 0, stream>>>(x, rs, XpH, XpL, WtH, WtL, emb, bu, 64,
                                                 state, zb, out);
}

// Round 16
// 439.596 us; speedup vs baseline: 1.0229x; 1.0229x over previous
//
#include <hip/hip_runtime.h>
#include <hip/hip_bf16.h>
#include <math.h>

#define B_ 64
#define N_ 1024
#define E_ 16

typedef unsigned short ushort_t;
typedef __attribute__((ext_vector_type(8))) short bf16x8;
typedef __attribute__((ext_vector_type(4))) float f32x4;

__device__ __forceinline__ float sigmoidf_(float x) {
  return 1.0f / (1.0f + __expf(-x));
}
__device__ __forceinline__ ushort_t f2bf(float f) {  // RNE
  unsigned int u = __float_as_uint(f);
  u = (u + 0x7fffu + ((u >> 16) & 1u)) >> 16;
  return (ushort_t)u;
}
__device__ __forceinline__ float bf2f(ushort_t h) { return __uint_as_float((unsigned)h << 16); }
__device__ __forceinline__ void gload16(const void* g, void* l) {
  __builtin_amdgcn_global_load_lds(
      (const __attribute__((address_space(1))) unsigned int*)g,
      (__attribute__((address_space(3))) unsigned int*)l, 16, 0, 0);
}

// ---------- A = softmax(relu(emb@emb^T)) -> hi/lo bf16 [n][m] (rows 0-1023 of stack) ----------
__global__ __launch_bounds__(256) void compute_A_kernel(const float* __restrict__ emb,
                                                        ushort_t* __restrict__ Ah,
                                                        ushort_t* __restrict__ Al) {
  __shared__ float embn[E_];
  __shared__ float red[256];
  const int n = blockIdx.x;
  const int t = threadIdx.x;
  if (t < E_) embn[t] = emb[n * E_ + t];
  __syncthreads();
  float s[4];
#pragma unroll
  for (int j = 0; j < 4; ++j) {
    const int m = j * 256 + t;
    const float* em = emb + m * E_;
    float acc = 0.f;
#pragma unroll
    for (int d = 0; d < E_; ++d) acc = fmaf(embn[d], em[d], acc);
    s[j] = fmaxf(acc, 0.f);
  }
  float mx = fmaxf(fmaxf(s[0], s[1]), fmaxf(s[2], s[3]));
  red[t] = mx;
  __syncthreads();
  for (int off = 128; off > 0; off >>= 1) {
    if (t < off) red[t] = fmaxf(red[t], red[t + off]);
    __syncthreads();
  }
  mx = red[0];
  __syncthreads();
  float e[4], lsum = 0.f;
#pragma unroll
  for (int j = 0; j < 4; ++j) { e[j] = __expf(s[j] - mx); lsum += e[j]; }
  red[t] = lsum;
  __syncthreads();
  for (int off = 128; off > 0; off >>= 1) {
    if (t < off) red[t] += red[t + off];
    __syncthreads();
  }
  const float inv = 1.0f / red[0];
#pragma unroll
  for (int j = 0; j < 4; ++j) {
    const float v = e[j] * inv;
    ushort_t h = f2bf(v);
    Ah[n * N_ + j * 256 + t] = h;
    Al[n * N_ + j * 256 + t] = f2bf(v - bf2f(h));
  }
}

// ---------- At[j][m] = A[m][j] for hi and lo (LDS tile transpose) ----------
__global__ __launch_bounds__(256) void transpose_A_kernel(const ushort_t* __restrict__ src1,
                                                          ushort_t* __restrict__ dst1,
                                                          const ushort_t* __restrict__ src2,
                                                          ushort_t* __restrict__ dst2) {
  __shared__ ushort_t tile[128][130];
  const int t = threadIdx.x;
  const int r0 = blockIdx.y << 7, c0 = blockIdx.x << 7;
  const ushort_t* src = src1;
  ushort_t* dst = dst1;
#pragma unroll
  for (int p = 0; p < 2; ++p) {
    if (p) { src = src2; dst = dst2; __syncthreads(); }
#pragma unroll
    for (int it = 0; it < 8; ++it) {
      const int id = it * 256 + t;
      const int row = id >> 4, ch = (id & 15) << 3;
      *(uint4*)&tile[row][ch] = *(const uint4*)&src[(size_t)(r0 + row) * 1024 + c0 + ch];
    }
    __syncthreads();
#pragma unroll
    for (int it = 0; it < 8; ++it) {
      const int id = it * 256 + t;
      const int row = id >> 4, ch = (id & 15) << 3;
      ushort_t v[8];
#pragma unroll
      for (int u = 0; u < 8; ++u) v[u] = tile[ch + u][row];
      *(uint4*)&dst[(size_t)(c0 + row) * 1024 + r0 + ch] = *(const uint4*)v;
    }
    __syncthreads();
  }
}

// ---------- cat(xA,xB)[b][n][c] -> T0t hi/lo [(b*128+c)][n] ----------
__global__ __launch_bounds__(256) void build_T0t_kernel(const float* __restrict__ xA,
                                                        const float* __restrict__ xB,
                                                        ushort_t* __restrict__ Th,
                                                        ushort_t* __restrict__ Tl) {
  __shared__ float tile[128][129];  // [c][n-local]
  const int t = threadIdx.x;
  const int b = blockIdx.y;
  const int n0 = blockIdx.x << 7;
  const int c4 = (t & 31) << 2, nl = t >> 5;
#pragma unroll
  for (int p = 0; p < 16; ++p) {
    const int n = nl + (p << 3);
    const float4 v = (c4 < 64)
        ? *(const float4*)&xA[((size_t)b << 16) + ((size_t)(n0 + n) << 6) + c4]
        : *(const float4*)&xB[((size_t)b << 16) + ((size_t)(n0 + n) << 6) + c4 - 64];
    tile[c4 + 0][n] = v.x; tile[c4 + 1][n] = v.y;
    tile[c4 + 2][n] = v.z; tile[c4 + 3][n] = v.w;
  }
  __syncthreads();
  const int c = t >> 1, nc = (t & 1) << 6;
  const size_t obase = ((size_t)(b << 7) + c) * 1024 + n0 + nc;
#pragma unroll
  for (int u = 0; u < 64; u += 4) {
    ushort4 h, l;
    float v0 = tile[c][nc + u + 0], v1 = tile[c][nc + u + 1];
    float v2 = tile[c][nc + u + 2], v3 = tile[c][nc + u + 3];
    h.x = f2bf(v0); l.x = f2bf(v0 - bf2f(h.x));
    h.y = f2bf(v1); l.y = f2bf(v1 - bf2f(h.y));
    h.z = f2bf(v2); l.z = f2bf(v2 - bf2f(h.z));
    h.w = f2bf(v3); l.w = f2bf(v3 - bf2f(h.w));
    *(ushort4*)&Th[obase + u] = h;
    *(ushort4*)&Tl[obase + u] = l;
  }
}

// ---------- rs[b][n][64] -> T0s hi/lo [(b*64+c)][n]  (update pass, s-half only) ----------
__global__ __launch_bounds__(256) void build_T0s_kernel(const float* __restrict__ rs,
                                                        ushort_t* __restrict__ Th,
                                                        ushort_t* __restrict__ Tl) {
  __shared__ float tile[64][129];  // [c][n-local]
  const int t = threadIdx.x;
  const int b = blockIdx.y;
  const int n0 = blockIdx.x << 7;
  const int c4 = (t & 15) << 2, nl = t >> 4;
#pragma unroll
  for (int p = 0; p < 8; ++p) {
    const int n = nl + (p << 4);
    const float4 v = *(const float4*)&rs[((size_t)b << 16) + ((size_t)(n0 + n) << 6) + c4];
    tile[c4 + 0][n] = v.x; tile[c4 + 1][n] = v.y;
    tile[c4 + 2][n] = v.z; tile[c4 + 3][n] = v.w;
  }
  __syncthreads();
  const int c = t >> 2, nc = (t & 3) << 5;
  const size_t obase = ((size_t)(b << 6) + c) * 1024 + n0 + nc;
#pragma unroll
  for (int u = 0; u < 32; u += 4) {
    ushort4 h, l;
    float v0 = tile[c][nc + u + 0], v1 = tile[c][nc + u + 1];
    float v2 = tile[c][nc + u + 2], v3 = tile[c][nc + u + 3];
    h.x = f2bf(v0); l.x = f2bf(v0 - bf2f(h.x));
    h.y = f2bf(v1); l.y = f2bf(v1 - bf2f(h.y));
    h.z = f2bf(v2); l.z = f2bf(v2 - bf2f(h.z));
    h.w = f2bf(v3); l.w = f2bf(v3 - bf2f(h.w));
    *(ushort4*)&Th[obase + u] = h;
    *(ushort4*)&Tl[obase + u] = l;
  }
}

// ---------- MFMA split-bf16 GEMM (R10-verified): D[n][j] = sum_m (Ah+Al)[n][m]*(Bh+Bl)[j][m] ----------
// MODE 0: stacked diffusion — rows 0-1023 = A (-> Xp slot 0), 1024-2047 = M=2A^2 (-> slot 128).
//         SPAN 128: gate; SPAN 64: update (j=b*64+cs -> Xp offset 64+cs).
// MODE 1: M-writer — v = 2*acc, row-major OutH/OutL [n][j].
template <int MODE, int SPAN>
__global__ __launch_bounds__(256, 2) void mfma_gemm_kernel(
    const ushort_t* __restrict__ Ah, const ushort_t* __restrict__ Al,   // stacked [2048][1024]
    const ushort_t* __restrict__ Bh, const ushort_t* __restrict__ Bl,   // [NJ][1024]
    ushort_t* __restrict__ OutH, ushort_t* __restrict__ OutL) {
  __shared__ ushort_t smem[4 * 128 * 64];  // 64 KB
  ushort_t* Ah_s = smem;
  ushort_t* Al_s = smem + 8192;
  ushort_t* Bh_s = smem + 16384;
  ushort_t* Bl_s = smem + 24576;
  const int t = threadIdx.x;
  const int wave = t >> 6, lane = t & 63;
  const int n0 = blockIdx.y << 7;   // stacked row base
  const int bcol = blockIdx.x;
  const int j0 = bcol << 7;
  const int wr = wave >> 1, wc = wave & 1;
  const int fr = lane & 15, fk = lane >> 4;

  f32x4 acc[4][4];
#pragma unroll
  for (int i = 0; i < 4; ++i)
#pragma unroll
    for (int j = 0; j < 4; ++j) acc[i][j] = (f32x4){0.f, 0.f, 0.f, 0.f};

  const int rsub = lane >> 3;
  const int cp = lane & 7;
  const int selem = (((cp << 4) ^ (rsub << 4)) >> 1);

  for (int k0 = 0; k0 < 1024; k0 += 64) {
    __syncthreads();
#pragma unroll
    for (int i = 0; i < 4; ++i) {
      const int q = (wave << 2) + i;
      const int row = (q << 3) + rsub;
      const int lo = (q << 9) + lane * 8;
      const size_t ga = (size_t)(n0 + row) * 1024 + k0 + selem;
      const size_t gb = (size_t)(j0 + row) * 1024 + k0 + selem;
      gload16(Ah + ga, Ah_s + lo);
      gload16(Al + ga, Al_s + lo);
      gload16(Bh + gb, Bh_s + lo);
      gload16(Bl + gb, Bl_s + lo);
    }
    __syncthreads();
#pragma unroll
    for (int ks = 0; ks < 2; ++ks) {
      bf16x8 ah[4], al[4], bh[4], bl[4];
#pragma unroll
      for (int mi = 0; mi < 4; ++mi) {
        const int r = (wr << 6) + (mi << 4) + fr;
        const int kb = ((ks << 6) + (fk << 4)) ^ ((r & 7) << 4);
        ah[mi] = *(const bf16x8*)((const char*)Ah_s + r * 128 + kb);
        al[mi] = *(const bf16x8*)((const char*)Al_s + r * 128 + kb);
      }
#pragma unroll
      for (int nj = 0; nj < 4; ++nj) {
        const int r = (wc << 6) + (nj << 4) + fr;
        const int kb = ((ks << 6) + (fk << 4)) ^ ((r & 7) << 4);
        bh[nj] = *(const bf16x8*)((const char*)Bh_s + r * 128 + kb);
        bl[nj] = *(const bf16x8*)((const char*)Bl_s + r * 128 + kb);
      }
#pragma unroll
      for (int mi = 0; mi < 4; ++mi)
#pragma unroll
        for (int nj = 0; nj < 4; ++nj) {
          acc[mi][nj] = __builtin_amdgcn_mfma_f32_16x16x32_bf16(ah[mi], bh[nj], acc[mi][nj], 0, 0, 0);
          acc[mi][nj] = __builtin_amdgcn_mfma_f32_16x16x32_bf16(ah[mi], bl[nj], acc[mi][nj], 0, 0, 0);
          acc[mi][nj] = __builtin_amdgcn_mfma_f32_16x16x32_bf16(al[mi], bh[nj], acc[mi][nj], 0, 0, 0);
        }
    }
  }

  __syncthreads();  // staging done; reuse smem as [128][128] hi/lo transpose tiles
  ushort_t* hiT = smem;            // 32 KB
  ushort_t* loT = smem + 16384;    // 32 KB
#pragma unroll
  for (int mi = 0; mi < 4; ++mi) {
    const int nl = (wr << 6) + (mi << 4) + (fk << 2);
#pragma unroll
    for (int nj = 0; nj < 4; ++nj) {
      const int jl = (wc << 6) + (nj << 4) + fr;
      const f32x4 vv = acc[mi][nj];
#pragma unroll
      for (int r = 0; r < 4; ++r) {
        const float v = (MODE == 1) ? 2.0f * vv[r] : vv[r];
        const ushort_t h = f2bf(v);
        hiT[(nl + r) * 128 + jl] = h;
        loT[(nl + r) * 128 + jl] = f2bf(v - bf2f(h));
      }
    }
  }
  __syncthreads();
  const int soff = (n0 >= 1024) ? 128 : 0;
  const int n0e = n0 & 1023;
#pragma unroll
  for (int rr = 0; rr < 8; ++rr) {
    const int id = rr * 256 + t;     // 2048 16B-chunks
    const int nl = id >> 4, ch = id & 15;
    size_t dstE;
    if (MODE == 1) {
      dstE = (size_t)(n0 + nl) * 1024 + j0 + ch * 8;
    } else if (SPAN == 128) {
      dstE = ((size_t)(n0e + nl) * 64 + bcol) * 256 + soff + ch * 8;
    } else {
      const int bb = bcol * 2 + (ch >> 3);
      dstE = ((size_t)(n0e + nl) * 64 + bb) * 256 + soff + 64 + (ch & 7) * 8;
    }
    *(uint4*)&OutH[dstE] = *(const uint4*)((const char*)hiT + nl * 256 + ch * 16);
    *(uint4*)&OutL[dstE] = *(const uint4*)((const char*)loT + nl * 256 + ch * 16);
  }
}

// ---------- pool transpose: WpT[o][ki][d] = Wp[d][k][i][o] (- Wp[d][2][i][o] if k==0) ----------
template <int OW>  // 128 gate, 64 update
__global__ __launch_bounds__(256) void wpt_kernel(const float* __restrict__ Wp,
                                                  float* __restrict__ WpT) {
  const int idx = blockIdx.x * 256 + threadIdx.x;  // OW*384
  const int ki = idx % 384;
  const int k = ki >> 7, i = ki & 127;
  const int o = idx / 384;
  float v[16];
#pragma unroll
  for (int d = 0; d < 16; ++d) v[d] = Wp[((size_t)d * 384 + ki) * OW + o];
  if (k == 0) {
#pragma unroll
    for (int d = 0; d < 16; ++d) v[d] -= Wp[((size_t)d * 384 + 256 + i) * OW + o];
  }
  float* dst = WpT + (size_t)idx * 16;
#pragma unroll
  for (int q = 0; q < 4; ++q) *(float4*)&dst[q * 4] = *(const float4*)&v[q * 4];
}

// ---------- reg-cached combine: Wt[o][n][ki] hi/lo = sum_d emb[n][d]*WpT[o][ki][d] ----------
// block = (one o, 128 nodes): 512 blocks (2/CU) for write-BW parallelism
__global__ __launch_bounds__(384) void wcombine5_kernel(const float* __restrict__ emb,
                                                        const float* __restrict__ WpT,  // [64][384][16] pre-offset
                                                        ushort_t* __restrict__ WtH,
                                                        ushort_t* __restrict__ WtL) {
  __shared__ float embs[128 * 16];      // 8 KB
  __shared__ ushort_t sH[8 * 384];      // 6 KB
  __shared__ ushort_t sL[8 * 384];      // 6 KB
  const int t = threadIdx.x;            // 0..383 = ki
  const int o = blockIdx.y;             // 0..63
  const int n0 = blockIdx.x << 7;       // node group of 128
  for (int i = t; i < 512; i += 384)
    *(float4*)&embs[i * 4] = *(const float4*)&emb[(size_t)n0 * 16 + i * 4];
  float wreg[16];
  {
    const float* src = WpT + (size_t)o * 6144 + t * 16;
#pragma unroll
    for (int q = 0; q < 4; ++q) *(float4*)&wreg[q * 4] = *(const float4*)&src[q * 4];
  }
  __syncthreads();
  for (int g = 0; g < 16; ++g) {
#pragma unroll
    for (int nl = 0; nl < 8; ++nl) {
      const float* e = &embs[(g * 8 + nl) * 16];
      float a = 0.f;
#pragma unroll
      for (int d = 0; d < 16; ++d) a = fmaf(e[d], wreg[d], a);
      const ushort_t h = f2bf(a);
      sH[nl * 384 + t] = h;
      sL[nl * 384 + t] = f2bf(a - bf2f(h));
    }
    __syncthreads();
    const size_t ob = ((size_t)o * 1024 + n0 + g * 8) * 384 + t * 8;
    *(uint4*)&WtH[ob] = *(const uint4*)&sH[t * 8];
    *(uint4*)&WtL[ob] = *(const uint4*)&sL[t * 8];
    __syncthreads();
  }
}

// ---------- per-node MFMA contraction (O=64) + GRU epilogue ----------
// MODE 0: dst = sigmoid(a)                  (z -> d_out)
// MODE 1: dst = sigmoid(a) * state          (rs)
// MODE 2: dst = zb*state + (1-zb)*tanh(a)   (final out)
template <int MODE>
__global__ __launch_bounds__(256, 2) void pernode_mfma_kernel(
    const float* __restrict__ xA, const float* __restrict__ xB,   // [b][n][64]
    const ushort_t* __restrict__ XpH, const ushort_t* __restrict__ XpL,  // [n][64][256]
    const ushort_t* __restrict__ WtH, const ushort_t* __restrict__ WtL,  // [o][n][384]
    const float* __restrict__ emb, const float* __restrict__ bsrc, int bstride,
    const float* __restrict__ state, const float* __restrict__ zb,
    float* __restrict__ dst) {
  __shared__ ushort_t xh_s[64 * 128];  // 16 KB each
  __shared__ ushort_t xl_s[64 * 128];
  __shared__ ushort_t wh_s[64 * 128];
  __shared__ ushort_t wl_s[64 * 128];
  __shared__ float embn[E_];
  __shared__ float bias[64];
  const int n = blockIdx.x;
  const int t = threadIdx.x;
  if (t < E_) embn[t] = emb[n * E_ + t];
  __syncthreads();
  if (t < 64) {
    float a = 0.f;
#pragma unroll
    for (int d = 0; d < E_; ++d) a = fmaf(embn[d], bsrc[d * bstride + t], a);
    bias[t] = a;
  }
  const int wave = t >> 6, lane = t & 63;
  const int fr = lane & 15, fq = lane >> 4;
  f32x4 acc[4];
#pragma unroll
  for (int i = 0; i < 4; ++i) acc[i] = (f32x4){0.f, 0.f, 0.f, 0.f};

#pragma unroll
  for (int s = 0; s < 3; ++s) {
    __syncthreads();
    if (s == 0) {  // k0 = concat(xA, xB) f32 -> hi/lo bf16, swizzled ds_write
      const int b = t >> 2, q = t & 3;
      const float* srcp = (q < 2)
          ? xA + ((size_t)b << 16) + ((size_t)n << 6) + (q << 5)
          : xB + ((size_t)b << 16) + ((size_t)n << 6) + ((q - 2) << 5);
      float v[32];
#pragma unroll
      for (int j = 0; j < 8; ++j) *(float4*)&v[j * 4] = *(const float4*)&srcp[j * 4];
      const int swz = (b & 7) << 4;
#pragma unroll
      for (int jc = 0; jc < 4; ++jc) {
        unsigned int hh[4], ll[4];
#pragma unroll
        for (int e = 0; e < 4; ++e) {
          const float a0 = v[jc * 8 + 2 * e], a1 = v[jc * 8 + 2 * e + 1];
          const ushort_t h0 = f2bf(a0), h1 = f2bf(a1);
          const ushort_t l0 = f2bf(a0 - bf2f(h0)), l1 = f2bf(a1 - bf2f(h1));
          hh[e] = (unsigned)h0 | ((unsigned)h1 << 16);
          ll[e] = (unsigned)l0 | ((unsigned)l1 << 16);
        }
        const int dstb = b * 256 + (((q << 6) + (jc << 4)) ^ swz);
        *(uint4*)((char*)xh_s + dstb) = make_uint4(hh[0], hh[1], hh[2], hh[3]);
        *(uint4*)((char*)xl_s + dstb) = make_uint4(ll[0], ll[1], ll[2], ll[3]);
      }
    } else {  // Xp slots via global_load_lds, pre-swizzled source
#pragma unroll
      for (int r = 0; r < 4; ++r) {
        const int id = r * 256 + t;
        const int row = id >> 4, ch = id & 15;
        const int selem = (((ch << 4) ^ ((row & 7) << 4)) >> 1);
        const size_t so = ((size_t)n * 64 + row) * 256 + (s - 1) * 128 + selem;
        gload16(XpH + so, xh_s + id * 8);
        gload16(XpL + so, xl_s + id * 8);
      }
    }
#pragma unroll
    for (int r = 0; r < 4; ++r) {
      const int id = r * 256 + t;
      const int row = id >> 4, ch = id & 15;
      const int selem = (((ch << 4) ^ ((row & 7) << 4)) >> 1);
      const size_t so = ((size_t)row * 1024 + n) * 384 + s * 128 + selem;  // Wt[o][n][ki]
      gload16(WtH + so, wh_s + id * 8);
      gload16(WtL + so, wl_s + id * 8);
    }
    __syncthreads();
#pragma unroll
    for (int ks = 0; ks < 4; ++ks) {
      bf16x8 ah[4], al[4];
#pragma unroll
      for (int mi = 0; mi < 4; ++mi) {
        const int r = (mi << 4) + fr;
        const int kb = ((ks << 6) + (fq << 4)) ^ ((r & 7) << 4);
        ah[mi] = *(const bf16x8*)((const char*)xh_s + r * 256 + kb);
        al[mi] = *(const bf16x8*)((const char*)xl_s + r * 256 + kb);
      }
      const int rw = (wave << 4) + fr;
      const int kbw = ((ks << 6) + (fq << 4)) ^ ((rw & 7) << 4);
      const bf16x8 wh = *(const bf16x8*)((const char*)wh_s + rw * 256 + kbw);
      const bf16x8 wl = *(const bf16x8*)((const char*)wl_s + rw * 256 + kbw);
#pragma unroll
      for (int mi = 0; mi < 4; ++mi) {
        acc[mi] = __builtin_amdgcn_mfma_f32_16x16x32_bf16(ah[mi], wh, acc[mi], 0, 0, 0);
        acc[mi] = __builtin_amdgcn_mfma_f32_16x16x32_bf16(al[mi], wh, acc[mi], 0, 0, 0);
        acc[mi] = __builtin_amdgcn_mfma_f32_16x16x32_bf16(ah[mi], wl, acc[mi], 0, 0, 0);
      }
    }
  }

  const int o = (wave << 4) + fr;
  const float bia = bias[o];
#pragma unroll
  for (int mi = 0; mi < 4; ++mi) {
    const int b0 = (mi << 4) + (fq << 2);
    const f32x4 vv = acc[mi];
#pragma unroll
    for (int r = 0; r < 4; ++r) {
      const int b = b0 + r;
      const size_t base = ((size_t)b << 16) + ((size_t)n << 6);
      const float a = vv[r] + bia;
      if (MODE == 0) {
        dst[base + o] = sigmoidf_(a);
      } else if (MODE == 1) {
        dst[base + o] = sigmoidf_(a) * state[base + o];
      } else {
        const float z = zb[base + o], st = state[base + o];
        dst[base + o] = z * st + (1.f - z) * tanhf(a);
      }
    }
  }
}

extern "C" void kernel_launch(void* const* d_in, const int* in_sizes, int n_in,
                              void* d_out, int out_size, void* d_ws, size_t ws_size,
                              hipStream_t stream) {
  const float* x     = (const float*)d_in[0];
  const float* state = (const float*)d_in[1];
  const float* emb   = (const float*)d_in[2];
  const float* Wg    = (const float*)d_in[3];
  const float* bg    = (const float*)d_in[4];
  const float* Wu    = (const float*)d_in[5];
  const float* bu    = (const float*)d_in[6];
  float* out = (float*)d_out;

  char* w = (char*)d_ws;
  ushort_t* AhS  = (ushort_t*)(w);                             // 4 MB [2048][1024]: A rows 0-1023, M rows 1024-2047
  ushort_t* AlS  = (ushort_t*)(w + ((size_t)4 << 20));         // 4
  ushort_t* Ath  = (ushort_t*)(w + ((size_t)8 << 20));         // 2
  ushort_t* Atl  = (ushort_t*)(w + ((size_t)10 << 20));        // 2
  ushort_t* T0th = (ushort_t*)(w + ((size_t)12 << 20));        // 16 (update reuses as T0s)
  ushort_t* T0tl = (ushort_t*)(w + ((size_t)28 << 20));        // 16
  ushort_t* XpH  = (ushort_t*)(w + ((size_t)44 << 20));        // 32  [n][64][256]
  ushort_t* XpL  = (ushort_t*)(w + ((size_t)76 << 20));        // 32
  ushort_t* WtH  = (ushort_t*)(w + ((size_t)108 << 20));       // 48  [o][n][384]
  ushort_t* WtL  = (ushort_t*)(w + ((size_t)156 << 20));       // 48
  float*    rs   = (float*)(w + ((size_t)204 << 20));          // 16
  float*    WpTg = (float*)(w + ((size_t)220 << 20));          // 3   [128][384][16]
  float*    WpTu = (float*)(w + ((size_t)223 << 20));          // 1.5 -> 224.5 MB
  ushort_t* Mh = AhS + (size_t)1024 * 1024;
  ushort_t* Ml = AlS + (size_t)1024 * 1024;
  float* zb = out;

  const dim3 ggd(64, 16);  // gate diffusion (stacked A+M rows)
  const dim3 gud(32, 16);  // update diffusion (s-half cols)
  const dim3 gm(8, 8);     // M-GEMM / transpose
  const dim3 gt(8, 64);
  const dim3 gc(8, 64);    // combine: (n-groups of 128, o)

  compute_A_kernel<<<N_, 256, 0, stream>>>(emb, AhS, AlS);
  transpose_A_kernel<<<gm, 256, 0, stream>>>(AhS, Ath, AlS, Atl);
  mfma_gemm_kernel<1, 128><<<gm, 256, 0, stream>>>(AhS, AlS, Ath, Atl, Mh, Ml);  // M = 2*A*A
  wpt_kernel<128><<<192, 256, 0, stream>>>(Wg, WpTg);
  wpt_kernel<64><<<96, 256, 0, stream>>>(Wu, WpTu);

  // ---- gate pass: one stacked GEMM computes Y1 = A*T0 and Y2 = M*T0 ----
  build_T0t_kernel<<<gt, 256, 0, stream>>>(x, state, T0th, T0tl);
  mfma_gemm_kernel<0, 128><<<ggd, 256, 0, stream>>>(AhS, AlS, T0th, T0tl, XpH, XpL);
  wcombine5_kernel<<<gc, 384, 0, stream>>>(emb, WpTg, WtH, WtL);
  pernode_mfma_kernel<0><<<N_, 256, 0, stream>>>(x, state, XpH, XpL, WtH, WtL, emb, bg, 128,
                                                 state, nullptr, zb);
  wcombine5_kernel<<<gc, 384, 0, stream>>>(emb, WpTg + (size_t)64 * 6144, WtH, WtL);
  pernode_mfma_kernel<1><<<N_, 256, 0, stream>>>(x, state, XpH, XpL, WtH, WtL, emb, bg + 64, 128,
                                                 state, nullptr, rs);

  // ---- update pass: diffuse only rs-half; x diffusion persists from gate ----
  wcombine5_kernel<<<gc, 384, 0, stream>>>(emb, WpTu, WtH, WtL);
  build_T0s_kernel<<<gt, 256, 0, stream>>>(rs, T0th, T0tl);
  mfma_gemm_kernel<0, 64><<<gud, 256, 0, stream>>>(AhS, AlS, T0th, T0tl, XpH, XpL);
  pernode_mfma_kernel<2><<<N_, 256, 0, stream>>>(x, rs, XpH, XpL, WtH, WtL, emb, bu, 64,
                                                 state, zb, out);
}